// Round 1
// baseline (269.602 us; speedup 1.0000x reference)
//
#include <hip/hip_runtime.h>

#define HH 16
#define TT 4096
#define DD 64

typedef __attribute__((ext_vector_type(4))) _Float16 half4;
typedef __attribute__((ext_vector_type(4))) float float4v;

// One block = 4 waves; each wave owns 16 consecutive q rows of one head.
// Swapped flash attention: St = K_tile * Q^T (MFMA), online softmax across
// lanes via xor-16/32 butterflies, PV as Ot = V^T * P^T (MFMA), all with
// v_mfma_f32_16x16x16_f16 (documented CDNA fragment layouts).
__global__ __launch_bounds__(256) void pa_fwd(
    const float* __restrict__ qg, const float* __restrict__ kg,
    const float* __restrict__ vg, const int* __restrict__ cu,
    float* __restrict__ outg)
{
    const int tid  = threadIdx.x;
    const int wave = tid >> 6;
    const int lane = tid & 63;
    const int lr   = lane & 15;   // column index (q row within wave / key row within tile)
    const int lg   = lane >> 4;   // 4-lane group id

    const int h  = blockIdx.x >> 6;                       // 64 q-blocks per head
    const int qb = ((blockIdx.x & 63) << 6) | (wave << 4); // first q row of this wave

    const int q_row = qb + lr;

    // segment bounds for this lane's q row (searchsorted semantics)
    int s = 0;
    while (cu[s + 1] <= q_row) ++s;
    const int seg_lo = cu[s];
    const int seg_hi = cu[s + 1];
    const int wlo = __shfl(seg_lo, 0);   // min over the wave's 16 rows
    const int whi = __shfl(seg_hi, 15);  // max over the wave's 16 rows

    // Q fragment (B operand of St MFMA), pre-scaled by 1/sqrt(D)
    const float* qrow = qg + ((size_t)h * TT + q_row) * DD;
    half4 qf[4];
#pragma unroll
    for (int ds = 0; ds < 4; ++ds) {
        float4v t4 = *(const float4v*)(qrow + ds * 16 + lg * 4);
#pragma unroll
        for (int j = 0; j < 4; ++j) qf[ds][j] = (_Float16)(t4[j] * 0.125f);
    }

    const float* kh = kg + (size_t)h * TT * DD;
    const float* vh = vg + (size_t)h * TT * DD;

    float4v acc[4];   // Ot[d = dt*16 + 4*lg + j][q = qb + lr]
#pragma unroll
    for (int dt = 0; dt < 4; ++dt) acc[dt] = (float4v){0.f, 0.f, 0.f, 0.f};
    float m_run = -1e30f;
    float lsum  = 0.f;

    for (int kvt = wlo & ~31; kvt < whi; kvt += 32) {
        // ---- scores: two 16-key tiles, St[key][q] ----
        float st[2][4];
        float tmax = -1e30f;
#pragma unroll
        for (int t = 0; t < 2; ++t) {
            float4v sa = (float4v){0.f, 0.f, 0.f, 0.f};
            const float* krow = kh + (size_t)(kvt + t * 16 + lr) * DD;
#pragma unroll
            for (int ds = 0; ds < 4; ++ds) {
                float4v t4 = *(const float4v*)(krow + ds * 16 + lg * 4);
                half4 kf;
#pragma unroll
                for (int j = 0; j < 4; ++j) kf[j] = (_Float16)t4[j];
                sa = __builtin_amdgcn_mfma_f32_16x16x16f16(kf, qf[ds], sa, 0, 0, 0);
            }
#pragma unroll
            for (int j = 0; j < 4; ++j) {
                const int key = kvt + t * 16 + lg * 4 + j;
                const float sv = (key >= seg_lo && key < seg_hi) ? sa[j] : -1e30f;
                st[t][j] = sv;
                tmax = fmaxf(tmax, sv);
            }
        }
        // per-q-row (column lr) reduction across the 4 key-groups
        tmax = fmaxf(tmax, __shfl_xor(tmax, 16));
        tmax = fmaxf(tmax, __shfl_xor(tmax, 32));
        const float m_new = fmaxf(m_run, tmax);
        const float alpha = __expf(m_run - m_new); // exp(0)=1 when both -1e30: self-heals (wiped by alpha=0 at first valid tile)

        float p[2][4];
        float psum = 0.f;
#pragma unroll
        for (int t = 0; t < 2; ++t)
#pragma unroll
            for (int j = 0; j < 4; ++j) {
                const float pv = __expf(st[t][j] - m_new); // masked -> exp(-huge)=0
                p[t][j] = pv;
                psum += pv;
            }
        psum += __shfl_xor(psum, 16);
        psum += __shfl_xor(psum, 32);
        lsum  = lsum * alpha + psum;
        m_run = m_new;

#pragma unroll
        for (int dt = 0; dt < 4; ++dt) {
            acc[dt][0] *= alpha; acc[dt][1] *= alpha;
            acc[dt][2] *= alpha; acc[dt][3] *= alpha;
        }

        // ---- PV: Ot += V^T * P^T, contraction over 16 keys per MFMA ----
#pragma unroll
        for (int t = 0; t < 2; ++t) {
            half4 pb;   // B operand: P^T[key = kvt+16t+4*lg+j][q = lr] — exactly st's D layout
#pragma unroll
            for (int j = 0; j < 4; ++j) pb[j] = (_Float16)p[t][j];
#pragma unroll
            for (int dt = 0; dt < 4; ++dt) {
                half4 vf; // A operand: V^T[d = dt*16+lr][key = kvt+16t+4*lg+j]
#pragma unroll
                for (int j = 0; j < 4; ++j)
                    vf[j] = (_Float16)vh[(size_t)(kvt + t * 16 + lg * 4 + j) * DD + dt * 16 + lr];
                acc[dt] = __builtin_amdgcn_mfma_f32_16x16x16f16(vf, pb, acc[dt], 0, 0, 0);
            }
        }
    }

    const float inv = 1.0f / lsum;
    float* orow = outg + ((size_t)h * TT + q_row) * DD;
#pragma unroll
    for (int dt = 0; dt < 4; ++dt) {
        float4v o;
#pragma unroll
        for (int j = 0; j < 4; ++j) o[j] = acc[dt][j] * inv;
        *(float4v*)(orow + dt * 16 + lg * 4) = o;
    }
}

extern "C" void kernel_launch(void* const* d_in, const int* in_sizes, int n_in,
                              void* d_out, int out_size, void* d_ws, size_t ws_size,
                              hipStream_t stream) {
    const float* q  = (const float*)d_in[0];
    const float* k  = (const float*)d_in[1];
    const float* v  = (const float*)d_in[2];
    const int*   cu = (const int*)d_in[3];
    float* out = (float*)d_out;

    dim3 grid(HH * (TT / 64));
    dim3 block(256);
    hipLaunchKernelGGL(pa_fwd, grid, block, 0, stream, q, k, v, cu, out);
}

// Round 3
// 141.168 us; speedup vs baseline: 1.9098x; 1.9098x over previous
//
#include <hip/hip_runtime.h>

#define HH 16
#define TT 4096
#define DD 64

typedef __attribute__((ext_vector_type(4))) _Float16 half4;
typedef __attribute__((ext_vector_type(4))) float float4v;

#define LSTRIDE 68   // f16 elements per LDS row: 64 + 4 pad (136 B, 8B-aligned)

// One block = 4 waves x 32 q rows = 128 q rows of one head.
// K/V staged cooperatively in LDS per 64-key tile, both row-major [key][d]
// with 136B padded stride. QK^T fragments: vector half4 LDS reads.
// PV V^T fragments: scalar u16 gather (bank-conflict-free), R1-proven math.
__global__ __launch_bounds__(256) void pa_fwd(
    const float* __restrict__ qg, const float* __restrict__ kg,
    const float* __restrict__ vg, const int* __restrict__ cu,
    float* __restrict__ outg)
{
    __shared__ __align__(16) _Float16 Kl[64 * LSTRIDE];
    __shared__ __align__(16) _Float16 Vl[64 * LSTRIDE];

    const int tid  = threadIdx.x;
    const int wave = tid >> 6;
    const int lane = tid & 63;
    const int lr   = lane & 15;
    const int lg   = lane >> 4;

    // XCD swizzle: grid 512 = 8 XCD x 64 contiguous work items (2 heads/XCD)
    const int bswz = ((int)blockIdx.x & 7) * 64 + ((int)blockIdx.x >> 3);
    const int h    = bswz >> 5;
    const int qblk = (bswz & 31) << 7;     // 128 q rows per block
    const int qb   = qblk + wave * 32;     // 32 q rows per wave

    const int q0 = qb + lr;
    const int q1 = qb + 16 + lr;

    // segment bounds (searchsorted semantics), monotone scan
    int s = 0;
    while (cu[s + 1] <= q0) ++s;
    const int lo0 = cu[s], hi0 = cu[s + 1];
    while (cu[s + 1] <= q1) ++s;
    const int lo1 = cu[s], hi1 = cu[s + 1];

    int sb = 0;
    while (cu[sb + 1] <= qblk) ++sb;
    const int blo = cu[sb];
    while (cu[sb + 1] <= qblk + 127) ++sb;
    const int bhi = cu[sb + 1];

    const int wlo = __shfl(lo0, 0);    // wave min key
    const int whi = __shfl(hi1, 15);   // wave max key

    // Q fragments (B operand), pre-scaled by 1/sqrt(64)
    const float* qrow0 = qg + ((size_t)h * TT + q0) * DD;
    const float* qrow1 = qg + ((size_t)h * TT + q1) * DD;
    half4 qf0[4], qf1[4];
#pragma unroll
    for (int ds = 0; ds < 4; ++ds) {
        float4v t0 = *(const float4v*)(qrow0 + ds * 16 + lg * 4);
        float4v t1 = *(const float4v*)(qrow1 + ds * 16 + lg * 4);
#pragma unroll
        for (int j = 0; j < 4; ++j) {
            qf0[ds][j] = (_Float16)(t0[j] * 0.125f);
            qf1[ds][j] = (_Float16)(t1[j] * 0.125f);
        }
    }

    const float* kh_ = kg + (size_t)h * TT * DD;
    const float* vh_ = vg + (size_t)h * TT * DD;

    // staging assignment: thread -> (key row, 16-float d part); covers K and V
    const int skey = tid >> 2;          // 0..63
    const int sdp  = (tid & 3) << 4;    // 0,16,32,48

    float4v acc0[4], acc1[4];
#pragma unroll
    for (int dt = 0; dt < 4; ++dt) { acc0[dt] = (float4v){0,0,0,0}; acc1[dt] = (float4v){0,0,0,0}; }
    float m0 = -1e30f, l0 = 0.f, m1 = -1e30f, l1 = 0.f;

    for (int kt = blo & ~63; kt < bhi; kt += 64) {
        __syncthreads();   // previous tile's LDS reads complete
        {
            int krow = kt + skey; if (krow > TT - 1) krow = TT - 1;
            const float4v* ks = (const float4v*)(kh_ + (size_t)krow * DD + sdp);
            const float4v* vs = (const float4v*)(vh_ + (size_t)krow * DD + sdp);
#pragma unroll
            for (int c = 0; c < 4; ++c) {
                float4v kf4 = ks[c];
                float4v vf4 = vs[c];
                half4 kh4, vh4;
#pragma unroll
                for (int j = 0; j < 4; ++j) { kh4[j] = (_Float16)kf4[j]; vh4[j] = (_Float16)vf4[j]; }
                *(half4*)(&Kl[skey * LSTRIDE + sdp + c * 4]) = kh4;
                *(half4*)(&Vl[skey * LSTRIDE + sdp + c * 4]) = vh4;
            }
        }
        __syncthreads();   // staging complete
        if (kt + 64 <= wlo || kt >= whi) continue;   // both barriers already executed

        // ---- QK^T: St[key][q] for 4 x 16-key quarters, both q frags ----
        float st0[4][4], st1[4][4];
#pragma unroll
        for (int t = 0; t < 4; ++t) {
            float4v sa0 = (float4v){0,0,0,0}, sa1 = (float4v){0,0,0,0};
            const int key_r = t * 16 + lr;
#pragma unroll
            for (int ds = 0; ds < 4; ++ds) {
                half4 kf = *(const half4*)(&Kl[key_r * LSTRIDE + ds * 16 + lg * 4]);
                sa0 = __builtin_amdgcn_mfma_f32_16x16x16f16(kf, qf0[ds], sa0, 0, 0, 0);
                sa1 = __builtin_amdgcn_mfma_f32_16x16x16f16(kf, qf1[ds], sa1, 0, 0, 0);
            }
#pragma unroll
            for (int j = 0; j < 4; ++j) {
                const int key = kt + t * 16 + lg * 4 + j;
                st0[t][j] = (key >= lo0 && key < hi0) ? sa0[j] : -1e30f;
                st1[t][j] = (key >= lo1 && key < hi1) ? sa1[j] : -1e30f;
            }
        }

        // ---- online softmax (per q row = lr; reduce over lg via xor16/32) ----
        float tx0 = -1e30f, tx1 = -1e30f;
#pragma unroll
        for (int t = 0; t < 4; ++t)
#pragma unroll
            for (int j = 0; j < 4; ++j) { tx0 = fmaxf(tx0, st0[t][j]); tx1 = fmaxf(tx1, st1[t][j]); }
        tx0 = fmaxf(tx0, __shfl_xor(tx0, 16)); tx0 = fmaxf(tx0, __shfl_xor(tx0, 32));
        tx1 = fmaxf(tx1, __shfl_xor(tx1, 16)); tx1 = fmaxf(tx1, __shfl_xor(tx1, 32));
        const float mn0 = fmaxf(m0, tx0), mn1 = fmaxf(m1, tx1);
        const float a0 = __expf(m0 - mn0), a1 = __expf(m1 - mn1);
        // all-masked tile while m==-1e30 gives p=1 garbage; self-heals: first
        // valid tile has a=exp(-1e30-real)=0, wiping acc and l. (R1-proven.)

        half4 pb0[4], pb1[4];
        float ps0 = 0.f, ps1 = 0.f;
#pragma unroll
        for (int t = 0; t < 4; ++t)
#pragma unroll
            for (int j = 0; j < 4; ++j) {
                const float e0 = __expf(st0[t][j] - mn0);
                const float e1 = __expf(st1[t][j] - mn1);
                ps0 += e0; ps1 += e1;
                pb0[t][j] = (_Float16)e0; pb1[t][j] = (_Float16)e1;
            }
        ps0 += __shfl_xor(ps0, 16); ps0 += __shfl_xor(ps0, 32);
        ps1 += __shfl_xor(ps1, 16); ps1 += __shfl_xor(ps1, 32);
        l0 = l0 * a0 + ps0; l1 = l1 * a1 + ps1;
        m0 = mn0; m1 = mn1;

#pragma unroll
        for (int dt = 0; dt < 4; ++dt)
#pragma unroll
            for (int j = 0; j < 4; ++j) { acc0[dt][j] *= a0; acc1[dt][j] *= a1; }

        // ---- PV: Ot += V^T * P^T; V^T fragments via u16 gather (R1 math) ----
#pragma unroll
        for (int t = 0; t < 4; ++t) {
#pragma unroll
            for (int dt = 0; dt < 4; ++dt) {
                half4 vf;  // A: V^T[d = dt*16+lr][key = t*16 + lg*4 + j]
#pragma unroll
                for (int j = 0; j < 4; ++j)
                    vf[j] = Vl[(t * 16 + lg * 4 + j) * LSTRIDE + dt * 16 + lr];
                acc0[dt] = __builtin_amdgcn_mfma_f32_16x16x16f16(vf, pb0[t], acc0[dt], 0, 0, 0);
                acc1[dt] = __builtin_amdgcn_mfma_f32_16x16x16f16(vf, pb1[t], acc1[dt], 0, 0, 0);
            }
        }
    }

    const float inv0 = 1.0f / l0;
    const float inv1 = 1.0f / l1;
    float* orow0 = outg + ((size_t)h * TT + q0) * DD;
    float* orow1 = outg + ((size_t)h * TT + q1) * DD;
#pragma unroll
    for (int dt = 0; dt < 4; ++dt) {
        float4v o0, o1;
#pragma unroll
        for (int j = 0; j < 4; ++j) { o0[j] = acc0[dt][j] * inv0; o1[j] = acc1[dt][j] * inv1; }
        *(float4v*)(orow0 + dt * 16 + lg * 4) = o0;
        *(float4v*)(orow1 + dt * 16 + lg * 4) = o1;
    }
}

extern "C" void kernel_launch(void* const* d_in, const int* in_sizes, int n_in,
                              void* d_out, int out_size, void* d_ws, size_t ws_size,
                              hipStream_t stream) {
    const float* q  = (const float*)d_in[0];
    const float* k  = (const float*)d_in[1];
    const float* v  = (const float*)d_in[2];
    const int*   cu = (const int*)d_in[3];
    float* out = (float*)d_out;

    dim3 grid(HH * (TT / 128));   // 512
    dim3 block(256);
    hipLaunchKernelGGL(pa_fwd, grid, block, 0, stream, q, k, v, cu, out);
}

// Round 4
// 100.477 us; speedup vs baseline: 2.6832x; 1.4050x over previous
//
#include <hip/hip_runtime.h>

#define HH 16
#define TT 4096
#define DD 64

typedef __attribute__((ext_vector_type(4))) _Float16 half4;
typedef __attribute__((ext_vector_type(8))) _Float16 half8;
typedef __attribute__((ext_vector_type(4))) float float4v;

#define LSK 72   // K row stride in f16 (144 B, 16B-aligned)
#define LSV 72   // Vt row stride in f16

// One block = 8 waves x 16 q rows = 128 q rows of one head; grid 512 (2/CU).
// K staged row-major [key][d]; V staged TRANSPOSED [d][key] so PV fragments
// are vector ds_read_b64. Global->reg loads issued before the read-drain
// barrier (T14-lite). Wave-uniform full-tile fast path skips masking.
__global__ __launch_bounds__(512, 4) void pa_fwd(
    const float* __restrict__ qg, const float* __restrict__ kg,
    const float* __restrict__ vg, const int* __restrict__ cu,
    float* __restrict__ outg)
{
    __shared__ __align__(16) _Float16 Kl[64 * LSK];
    __shared__ __align__(16) _Float16 Vl[64 * LSV];

    const int tid  = threadIdx.x;
    const int wave = tid >> 6;
    const int lane = tid & 63;
    const int lr   = lane & 15;
    const int lg   = lane >> 4;

    // XCD swizzle: grid 512 = 8 XCD x 64 contiguous work items (2 heads/XCD)
    const int bswz = ((int)blockIdx.x & 7) * 64 + ((int)blockIdx.x >> 3);
    const int h    = bswz >> 5;
    const int qblk = (bswz & 31) << 7;     // 128 q rows per block
    const int qb   = qblk + wave * 16;     // 16 q rows per wave
    const int q    = qb + lr;

    // per-row segment bounds (searchsorted semantics)
    int s = 0;
    while (cu[s + 1] <= q) ++s;
    const int lo = cu[s], hi = cu[s + 1];

    // block-level staging range
    int sb = 0;
    while (cu[sb + 1] <= qblk) ++sb;
    const int blo = cu[sb];
    while (cu[sb + 1] <= qblk + 127) ++sb;
    const int bhi = cu[sb + 1];

    const int wlo = __shfl(lo, 0);    // wave min key
    const int whi = __shfl(hi, 15);   // wave max key
    const int mlo = __shfl(lo, 15);   // max lo over wave's rows
    const int mhi = __shfl(hi, 0);    // min hi over wave's rows

    // Q fragment (B operand), pre-scaled by 1/sqrt(64)
    const float* qrow = qg + ((size_t)h * TT + q) * DD;
    half4 qf[4];
#pragma unroll
    for (int ds = 0; ds < 4; ++ds) {
        float4v t4 = *(const float4v*)(qrow + ds * 16 + lg * 4);
#pragma unroll
        for (int j = 0; j < 4; ++j) qf[ds][j] = (_Float16)(t4[j] * 0.125f);
    }

    const float* kh_ = kg + (size_t)h * TT * DD;
    const float* vh_ = vg + (size_t)h * TT * DD;

    // staging assignments
    const int skey = tid >> 3;            // K: key row 0..63
    const int sd   = (tid & 7) << 3;      // K: d part 0,8,...,56
    const int vd   = tid & 63;            // V: d column 0..63
    const int voct = tid >> 6;            // V: key octet 0..7

    float4v acc[4];
#pragma unroll
    for (int dt = 0; dt < 4; ++dt) acc[dt] = (float4v){0.f, 0.f, 0.f, 0.f};
    float m_run = -1e30f, lsum = 0.f;

    for (int kt = blo & ~63; kt < bhi; kt += 64) {
        // ---- issue global loads early (overlap the read-drain barrier) ----
        int krow = kt + skey; if (krow > TT - 1) krow = TT - 1;
        const float* kp = kh_ + (size_t)krow * DD + sd;
        float4v ka = *(const float4v*)kp;
        float4v kb = *(const float4v*)(kp + 4);

        float vv[8];
#pragma unroll
        for (int c = 0; c < 8; ++c) {
            int vrow = kt + voct * 8 + c; if (vrow > TT - 1) vrow = TT - 1;
            vv[c] = vh_[(size_t)vrow * DD + vd];   // coalesced per c
        }

        __syncthreads();   // all waves done reading previous tile
        {
            half8 hk;
#pragma unroll
            for (int j = 0; j < 4; ++j) { hk[j] = (_Float16)ka[j]; hk[4 + j] = (_Float16)kb[j]; }
            *(half8*)(&Kl[skey * LSK + sd]) = hk;
            half8 hv;
#pragma unroll
            for (int c = 0; c < 8; ++c) hv[c] = (_Float16)vv[c];
            *(half8*)(&Vl[vd * LSV + voct * 8]) = hv;   // transposed: Vt[d][key]
        }
        __syncthreads();   // staging visible
        if (kt + 64 <= wlo || kt >= whi) continue;   // barriers already executed

        // ---- QK^T: St[key][q] for 4 x 16-key quarters ----
        float st[4][4];
        const bool fullv = (kt >= mlo) && (kt + 64 <= mhi);  // wave-uniform
#pragma unroll
        for (int t = 0; t < 4; ++t) {
            float4v sa = (float4v){0.f, 0.f, 0.f, 0.f};
            const int key_r = t * 16 + lr;
#pragma unroll
            for (int ds = 0; ds < 4; ++ds) {
                half4 kf = *(const half4*)(&Kl[key_r * LSK + ds * 16 + lg * 4]);
                sa = __builtin_amdgcn_mfma_f32_16x16x16f16(kf, qf[ds], sa, 0, 0, 0);
            }
            if (fullv) {
#pragma unroll
                for (int j = 0; j < 4; ++j) st[t][j] = sa[j];
            } else {
#pragma unroll
                for (int j = 0; j < 4; ++j) {
                    const int key = kt + t * 16 + lg * 4 + j;
                    st[t][j] = (key >= lo && key < hi) ? sa[j] : -1e30f;
                }
            }
        }

        // ---- online softmax (per q row = lr; reduce over lg via xor16/32) ----
        float tx = -1e30f;
#pragma unroll
        for (int t = 0; t < 4; ++t)
#pragma unroll
            for (int j = 0; j < 4; ++j) tx = fmaxf(tx, st[t][j]);
        tx = fmaxf(tx, __shfl_xor(tx, 16));
        tx = fmaxf(tx, __shfl_xor(tx, 32));
        const float mn = fmaxf(m_run, tx);
        const float a  = __expf(m_run - mn);
        // all-masked tile while m==-1e30 gives p=1 garbage; self-heals: first
        // valid tile has a=exp(-1e30-real)=0, wiping acc and l. (R1/R3-proven.)

        half4 pb[4];
        float ps = 0.f;
#pragma unroll
        for (int t = 0; t < 4; ++t)
#pragma unroll
            for (int j = 0; j < 4; ++j) {
                const float e = __expf(st[t][j] - mn);
                ps += e;
                pb[t][j] = (_Float16)e;
            }
        ps += __shfl_xor(ps, 16);
        ps += __shfl_xor(ps, 32);
        lsum = lsum * a + ps;
        m_run = mn;

#pragma unroll
        for (int dt = 0; dt < 4; ++dt)
#pragma unroll
            for (int j = 0; j < 4; ++j) acc[dt][j] *= a;

        // ---- PV: Ot += V^T * P^T; V^T fragments now vector b64 reads ----
#pragma unroll
        for (int t = 0; t < 4; ++t)
#pragma unroll
            for (int dt = 0; dt < 4; ++dt) {
                half4 vf = *(const half4*)(&Vl[(dt * 16 + lr) * LSV + t * 16 + lg * 4]);
                acc[dt] = __builtin_amdgcn_mfma_f32_16x16x16f16(vf, pb[t], acc[dt], 0, 0, 0);
            }
    }

    const float inv = 1.0f / lsum;
    float* orow = outg + ((size_t)h * TT + q) * DD;
#pragma unroll
    for (int dt = 0; dt < 4; ++dt) {
        float4v o;
#pragma unroll
        for (int j = 0; j < 4; ++j) o[j] = acc[dt][j] * inv;
        *(float4v*)(orow + dt * 16 + lg * 4) = o;
    }
}

extern "C" void kernel_launch(void* const* d_in, const int* in_sizes, int n_in,
                              void* d_out, int out_size, void* d_ws, size_t ws_size,
                              hipStream_t stream) {
    const float* q  = (const float*)d_in[0];
    const float* k  = (const float*)d_in[1];
    const float* v  = (const float*)d_in[2];
    const int*   cu = (const int*)d_in[3];
    float* out = (float*)d_out;

    dim3 grid(HH * (TT / 128));   // 512
    dim3 block(512);
    hipLaunchKernelGGL(pa_fwd, grid, block, 0, stream, q, k, v, cu, out);
}